// Round 7
// baseline (90.630 us; speedup 1.0000x reference)
//
#include <hip/hip_runtime.h>

#define NPART   2048
#define NCOMP   8192
#define NBATCH  8
#define THRESH  0.05f
#define FLTMAX  3.4028235e38f

#define TPTS    512                        // completed points per tile
#define NTILE   ((NBATCH * NCOMP) / TPTS)  // 128 point-tiles
#define NHALF   2                          // partial halves per tile
#define HPART   (NPART / NHALF)            // 1024 partials per block
#define WAVES   16
#define SEGLEN  (HPART / WAVES)            // 64 partials per wave
#define PPT     (TPTS / 64)                // 8 points per thread
#define GRID    (NTILE * NHALF)            // 256 blocks
#define TILB    (NCOMP / TPTS)             // 16 tiles per batch

// ws layout: [0,512) tickets u32[128]; [512,1536) tileslots float2[128];
//            [2048, 2048+512KB) halfmin float[128][2][512]
#define WS_SLOTS_OFF 512
#define WS_HALF_OFF  2048

__global__ __launch_bounds__(1024, 4) void pml_main(
    const float* __restrict__ completed,
    const float* __restrict__ partial,
    unsigned int* __restrict__ tickets,
    float2* __restrict__ tileslots,
    float* __restrict__ halfmin)
{
    const int tid  = threadIdx.x;
    const int lane = tid & 63;
    const int wave = tid >> 6;               // == partial segment (wave-uniform)
    const int tile = blockIdx.x >> 1;        // 0..127
    const int half = blockIdx.x & 1;         // which 1024-partial half
    const int batch = tile / TILB;
    const int tilb  = tile % TILB;

    __shared__ float4 sp[HPART];             // 16 KB (x,y,z,|p|^2)
    __shared__ float  smin[TPTS][WAVES + 1]; // 34 KB, pitch 17 -> 2-way (free)
    __shared__ float  sc2[TPTS];
    __shared__ float        rs[8];
    __shared__ unsigned int rc[8];
    __shared__ int isLast;

    // ---- stage this half's 1024 partials, precompute |p|^2 ----
    {
        const float* pb = partial + ((size_t)batch * NPART + (size_t)half * HPART) * 3;
        float x = pb[3 * tid + 0];
        float y = pb[3 * tid + 1];
        float z = pb[3 * tid + 2];
        sp[tid] = make_float4(x, y, z, fmaf(x, x, fmaf(y, y, z * z)));
    }

    // ---- this thread's 8 completed points (same 512 pts for every wave) ----
    const float* cb = completed + ((size_t)batch * NCOMP + (size_t)tilb * TPTS) * 3;
    float nx[PPT], ny[PPT], nz[PPT], c2[PPT];
    #pragma unroll
    for (int k = 0; k < PPT; ++k) {
        int p = lane + k * 64;
        float x = cb[3 * p + 0];
        float y = cb[3 * p + 1];
        float z = cb[3 * p + 2];
        nx[k] = -2.0f * x;
        ny[k] = -2.0f * y;
        nz[k] = -2.0f * z;
        c2[k] = fmaf(x, x, fmaf(y, y, z * z));
    }

    __syncthreads();

    // ---- scan this wave's 64 partials for 8 points ----
    // t = |p|^2 - 2 c.p ; per 4 partials per point: 3 fma x4 + 2 v_min3
    const float4* s = sp + wave * SEGLEN;
    float acc[PPT];
    #pragma unroll
    for (int k = 0; k < PPT; ++k) acc[k] = FLTMAX;

    for (int j = 0; j < SEGLEN; j += 4) {
        float4 p0 = s[j + 0];
        float4 p1 = s[j + 1];
        float4 p2 = s[j + 2];
        float4 p3 = s[j + 3];
        #pragma unroll
        for (int k = 0; k < PPT; ++k) {
            float t0 = fmaf(p0.x, nx[k], fmaf(p0.y, ny[k], fmaf(p0.z, nz[k], p0.w)));
            float t1 = fmaf(p1.x, nx[k], fmaf(p1.y, ny[k], fmaf(p1.z, nz[k], p1.w)));
            float t2 = fmaf(p2.x, nx[k], fmaf(p2.y, ny[k], fmaf(p2.z, nz[k], p2.w)));
            float t3 = fmaf(p3.x, nx[k], fmaf(p3.y, ny[k], fmaf(p3.z, nz[k], p3.w)));
            // fuses to 2x v_min3_f32
            acc[k] = fminf(fminf(fminf(fminf(acc[k], t0), t1), t2), t3);
        }
    }

    #pragma unroll
    for (int k = 0; k < PPT; ++k) {
        int p = lane + k * 64;
        smin[p][wave] = acc[k];              // bank (17p+wave)%32: 2-way, free
        if (wave == 0) sc2[p] = c2[k];
    }
    __syncthreads();

    // ---- per-point half-min (+c2, unclamped) -> ws exchange buffer ----
    if (tid < TPTS) {
        float t = smin[tid][0];
        #pragma unroll
        for (int g = 1; g < WAVES; ++g) t = fminf(t, smin[tid][g]);
        halfmin[((size_t)tile * NHALF + half) * TPTS + tid] = sc2[tid] + t;
    }
    __threadfence();                         // drain own stores, L2 writeback
    __syncthreads();

    if (tid == 0) {
        unsigned int old = atomicAdd(&tickets[tile], 1u);   // 128 separate lines
        isLast = (old == 1);
        if (old == 1) __threadfence();       // acquire: invalidate stale caches
    }
    __syncthreads();

    // ---- second sibling combines halves, masks, reduces the tile ----
    if (isLast) {
        float        v = 0.0f;
        unsigned int c = 0u;
        if (tid < TPTS) {
            float a = halfmin[((size_t)tile * NHALF + 0) * TPTS + tid];
            float b = halfmin[((size_t)tile * NHALF + 1) * TPTS + tid];
            float m = fmaxf(fminf(a, b), 0.0f);
            if (m < THRESH) { v = m; c = 1u; }
            #pragma unroll
            for (int off = 32; off >= 1; off >>= 1) {
                v += __shfl_down(v, off, 64);
                c += __shfl_down(c, off, 64);
            }
            if (lane == 0) { rs[wave] = v; rc[wave] = c; }
        }
        __syncthreads();
        if (tid == 0) {
            float        bs = 0.0f;
            unsigned int bc = 0u;
            #pragma unroll
            for (int w = 0; w < TPTS / 64; ++w) { bs += rs[w]; bc += rc[w]; }
            tileslots[tile] = make_float2(bs, (float)bc);
        }
    }
}

__global__ __launch_bounds__(64) void pml_fin(
    const float2* __restrict__ tileslots,
    float* __restrict__ out)
{
    const int lane = threadIdx.x;
    float2 s0 = tileslots[lane];
    float2 s1 = tileslots[lane + 64];
    float s = s0.x + s1.x;
    float c = s0.y + s1.y;
    #pragma unroll
    for (int off = 32; off >= 1; off >>= 1) {
        s += __shfl_down(s, off, 64);
        c += __shfl_down(c, off, 64);
    }
    if (lane == 0)
        *out = (c > 0.0f) ? (s / (c + 1e-6f)) : 0.0f;   // WEIGHT = 1.0
}

extern "C" void kernel_launch(void* const* d_in, const int* in_sizes, int n_in,
                              void* d_out, int out_size, void* d_ws, size_t ws_size,
                              hipStream_t stream) {
    const float* completed = (const float*)d_in[0];  // (8, 8192, 3) f32
    const float* partial   = (const float*)d_in[1];  // (8, 2048, 3) f32
    float* out = (float*)d_out;

    unsigned int* tickets   = (unsigned int*)d_ws;
    float2*       tileslots = (float2*)((char*)d_ws + WS_SLOTS_OFF);
    float*        halfmin   = (float*)((char*)d_ws + WS_HALF_OFF);

    // tickets must start at 0 every call (ws poisoned once, never re-poisoned)
    hipMemsetAsync(d_ws, 0, 512, stream);

    pml_main<<<dim3(GRID), dim3(1024), 0, stream>>>(
        completed, partial, tickets, tileslots, halfmin);
    pml_fin<<<dim3(1), dim3(64), 0, stream>>>(tileslots, out);
}

// Round 8
// 29.320 us; speedup vs baseline: 3.0911x; 3.0911x over previous
//
#include <hip/hip_runtime.h>

#define NPART   2048
#define NCOMP   8192
#define NBATCH  8
#define THRESH  0.05f
#define FLTMAX  3.4028235e38f

#define WAVES   16                         // per block
#define CHUNK   (NPART / WAVES)            // 128 partials per wave (2 per lane)
#define PPT     4                          // completed points per thread
#define PTSBLK  (64 * PPT)                 // 256 completed points per block
#define BLKSPB  (NCOMP / PTSBLK)           // 32 blocks per batch
#define GRID    (NBATCH * BLKSPB)          // 256 blocks, 16 waves each

// wave-wide broadcast of lane L's value: v_readlane_b32 -> SGPR (no memory,
// no waitcnt -- this is what replaces the inner-loop ds_read_b128)
__device__ __forceinline__ float bcast(float v, int L) {
    return __int_as_float(__builtin_amdgcn_readlane(__float_as_int(v), L));
}

__global__ __launch_bounds__(1024, 4) void pml_main(
    const float* __restrict__ completed,
    const float* __restrict__ partial,
    float2* __restrict__ slots_out)
{
    const int tid  = threadIdx.x;
    const int lane = tid & 63;
    const int wave = tid >> 6;               // 0..15, owns a 128-partial chunk
    const int batch = blockIdx.x >> 5;
    const int blkb  = blockIdx.x & (BLKSPB - 1);

    __shared__ float smin[PTSBLK][WAVES + 1]; // 17 KB, pitch 17 -> 2-way (free)
    __shared__ float sc2[PTSBLK];
    __shared__ float        rs[PTSBLK / 64];
    __shared__ unsigned int rc[PTSBLK / 64];

    // ---- this wave's 128 partials -> 2 float4 per lane (registers, not LDS) ----
    const float* pb = partial + ((size_t)batch * NPART + (size_t)wave * CHUNK) * 3;
    float q0x = pb[3 * lane + 0];
    float q0y = pb[3 * lane + 1];
    float q0z = pb[3 * lane + 2];
    float q1x = pb[3 * (lane + 64) + 0];
    float q1y = pb[3 * (lane + 64) + 1];
    float q1z = pb[3 * (lane + 64) + 2];
    float q0w = fmaf(q0x, q0x, fmaf(q0y, q0y, q0z * q0z));
    float q1w = fmaf(q1x, q1x, fmaf(q1y, q1y, q1z * q1z));

    // ---- this thread's 4 completed points (every wave holds the same 256) ----
    const float* cb = completed + ((size_t)batch * NCOMP + (size_t)blkb * PTSBLK) * 3;
    float nx[PPT], ny[PPT], nz[PPT], c2[PPT];
    #pragma unroll
    for (int k = 0; k < PPT; ++k) {
        int p = lane + k * 64;
        float x = cb[3 * p + 0];
        float y = cb[3 * p + 1];
        float z = cb[3 * p + 2];
        nx[k] = -2.0f * x;
        ny[k] = -2.0f * y;
        nz[k] = -2.0f * z;
        c2[k] = fmaf(x, x, fmaf(y, y, z * z));
    }

    // ---- scan: broadcast each of the wave's 128 partials from registers ----
    // t = |p|^2 - 2 c.p ; per L: 8 readlane + 4pts x (6 fma + min3) -- pure
    // VALU issue, zero LDS traffic, zero lgkmcnt stalls.
    float acc[PPT];
    #pragma unroll
    for (int k = 0; k < PPT; ++k) acc[k] = FLTMAX;

    #pragma unroll 8
    for (int L = 0; L < 64; ++L) {
        float px = bcast(q0x, L), py = bcast(q0y, L);
        float pz = bcast(q0z, L), pw = bcast(q0w, L);
        float rx = bcast(q1x, L), ry = bcast(q1y, L);
        float rz = bcast(q1z, L), rw = bcast(q1w, L);
        #pragma unroll
        for (int k = 0; k < PPT; ++k) {
            float t0 = fmaf(px, nx[k], fmaf(py, ny[k], fmaf(pz, nz[k], pw)));
            float t1 = fmaf(rx, nx[k], fmaf(ry, ny[k], fmaf(rz, nz[k], rw)));
            acc[k] = fminf(acc[k], fminf(t0, t1));   // fuses to v_min3_f32
        }
    }

    // ---- cross-wave combine via LDS (outside the hot loop) ----
    #pragma unroll
    for (int k = 0; k < PPT; ++k) {
        int p = lane + k * 64;
        smin[p][wave] = acc[k];          // banks (17p+w)%32: 2 lanes/bank, free
        if (wave == 0) sc2[p] = c2[k];
    }
    __syncthreads();

    float        v = 0.0f;
    unsigned int c = 0u;
    if (tid < PTSBLK) {
        float t = smin[tid][0];
        #pragma unroll
        for (int g = 1; g < WAVES; ++g) t = fminf(t, smin[tid][g]);
        float m = fmaxf(sc2[tid] + t, 0.0f);
        if (m < THRESH) { v = m; c = 1u; }
        #pragma unroll
        for (int off = 32; off >= 1; off >>= 1) {
            v += __shfl_down(v, off, 64);
            c += __shfl_down(c, off, 64);
        }
        if ((tid & 63) == 0) { rs[tid >> 6] = v; rc[tid >> 6] = c; }
    }
    __syncthreads();
    if (tid == 0) {
        float        bs = 0.0f;
        unsigned int bc = 0u;
        #pragma unroll
        for (int w = 0; w < PTSBLK / 64; ++w) { bs += rs[w]; bc += rc[w]; }
        // plain store to a private slot: no atomics, no fence, no ticket
        slots_out[blockIdx.x] = make_float2(bs, (float)bc);
    }
}

__global__ __launch_bounds__(256) void pml_fin(
    const float2* __restrict__ slots_in,
    float* __restrict__ out)
{
    const int tid = threadIdx.x;
    float2 sl = slots_in[tid];               // GRID == 256 == blockDim
    float s = sl.x, c = sl.y;
    #pragma unroll
    for (int off = 32; off >= 1; off >>= 1) {
        s += __shfl_down(s, off, 64);
        c += __shfl_down(c, off, 64);
    }
    __shared__ float ss[4], sc[4];
    if ((tid & 63) == 0) { ss[tid >> 6] = s; sc[tid >> 6] = c; }
    __syncthreads();
    if (tid == 0) {
        float s2 = ss[0] + ss[1] + ss[2] + ss[3];
        float c2 = sc[0] + sc[1] + sc[2] + sc[3];
        *out = (c2 > 0.0f) ? (s2 / (c2 + 1e-6f)) : 0.0f;   // WEIGHT = 1.0
    }
}

extern "C" void kernel_launch(void* const* d_in, const int* in_sizes, int n_in,
                              void* d_out, int out_size, void* d_ws, size_t ws_size,
                              hipStream_t stream) {
    const float* completed = (const float*)d_in[0];  // (8, 8192, 3) f32
    const float* partial   = (const float*)d_in[1];  // (8, 2048, 3) f32
    float* out = (float*)d_out;
    float2* slots = (float2*)d_ws;                   // 256 slots, all written
                                                     // before fin reads them:
                                                     // no memset node needed

    pml_main<<<dim3(GRID), dim3(1024), 0, stream>>>(completed, partial, slots);
    pml_fin<<<dim3(1), dim3(256), 0, stream>>>(slots, out);
}

// Round 9
// 21.517 us; speedup vs baseline: 4.2119x; 1.3626x over previous
//
#include <hip/hip_runtime.h>

#define NPART   2048
#define NCOMP   8192
#define NBATCH  8
#define THRESH  0.05f
#define FLTMAX  3.4028235e38f

#define SLOTS   32                        // point-slots per block
#define SEGS    32                        // partial segments (tid>>5)
#define SEGLEN  (NPART / SEGS)            // 64 partials per segment
#define PPT     8                         // completed points per thread
#define PTSBLK  (SLOTS * PPT)             // 256 completed points per block
#define BLKSPB  (NCOMP / PTSBLK)          // 32 blocks per batch
#define GRID    (NBATCH * BLKSPB)         // 256 blocks, 16 waves each
#define WAVES   16

__global__ __launch_bounds__(1024, 4) void pml_main(
    const float* __restrict__ completed,
    const float* __restrict__ partial,
    float2* __restrict__ slots_out)
{
    const int tid   = threadIdx.x;
    const int lane  = tid & 63;
    const int slot  = tid & (SLOTS - 1);
    const int seg   = tid >> 5;              // 0..31; half-wave uniform
    const int wave  = tid >> 6;
    const int batch = blockIdx.x >> 5;
    const int blkb  = blockIdx.x & (BLKSPB - 1);

    __shared__ float smin[PTSBLK][WAVES + 1]; // 17 KB, pitch 17 -> 2-way (free)
    __shared__ float sc2[PTSBLK];
    __shared__ float        rs[PTSBLK / 64];
    __shared__ unsigned int rc[PTSBLK / 64];

    // ---- this thread's 8 completed points (stride-32 -> coalesced) ----
    const float* cb = completed + ((size_t)batch * NCOMP + (size_t)blkb * PTSBLK) * 3;
    float nx[PPT], ny[PPT], nz[PPT], c2[PPT];
    #pragma unroll
    for (int k = 0; k < PPT; ++k) {
        int p = slot + k * SLOTS;
        float x = cb[3 * p + 0];
        float y = cb[3 * p + 1];
        float z = cb[3 * p + 2];
        nx[k] = -2.0f * x;
        ny[k] = -2.0f * y;
        nz[k] = -2.0f * z;
        c2[k] = fmaf(x, x, fmaf(y, y, z * z));
    }

    // ---- scan this segment's 64 partials straight from global/L1 ----
    // Per-lane addresses are runtime-uniform per half-wave: the TA coalesces
    // each dwordx4 into 2 L1 transactions (24 KB/batch fits the 32 KB L1).
    // No LDS staging, no lgkmcnt in the hot loop -- loads ride vmcnt and
    // software-pipeline. |p|^2 recomputed in-register (3 VALU/partial).
    // Base = partial + batch*24KB + seg*768B: 16B-aligned, 48B per 4 partials.
    const float4* pv = reinterpret_cast<const float4*>(
        partial + ((size_t)batch * NPART + (size_t)seg * SEGLEN) * 3);

    float acc[PPT];
    #pragma unroll
    for (int k = 0; k < PPT; ++k) acc[k] = FLTMAX;

    for (int i = 0; i < SEGLEN / 4; ++i) {
        float4 r0 = pv[3 * i + 0];           // p0x p0y p0z p1x
        float4 r1 = pv[3 * i + 1];           // p1y p1z p2x p2y
        float4 r2 = pv[3 * i + 2];           // p2z p3x p3y p3z
        float p0w = fmaf(r0.x, r0.x, fmaf(r0.y, r0.y, r0.z * r0.z));
        float p1w = fmaf(r0.w, r0.w, fmaf(r1.x, r1.x, r1.y * r1.y));
        float p2w = fmaf(r1.z, r1.z, fmaf(r1.w, r1.w, r2.x * r2.x));
        float p3w = fmaf(r2.y, r2.y, fmaf(r2.z, r2.z, r2.w * r2.w));
        #pragma unroll
        for (int k = 0; k < PPT; ++k) {
            float t0 = fmaf(r0.x, nx[k], fmaf(r0.y, ny[k], fmaf(r0.z, nz[k], p0w)));
            float t1 = fmaf(r0.w, nx[k], fmaf(r1.x, ny[k], fmaf(r1.y, nz[k], p1w)));
            float t2 = fmaf(r1.z, nx[k], fmaf(r1.w, ny[k], fmaf(r2.x, nz[k], p2w)));
            float t3 = fmaf(r2.y, nx[k], fmaf(r2.z, ny[k], fmaf(r2.w, nz[k], p3w)));
            // fuses to 2x v_min3_f32; 8 independent chains across k
            acc[k] = fminf(fminf(fminf(fminf(acc[k], t0), t1), t2), t3);
        }
    }

    // ---- fold the wave's seg pair via xor-32 shuffle, one LDS write ----
    #pragma unroll
    for (int k = 0; k < PPT; ++k) {
        float t = fminf(acc[k], __int_as_float(
            __shfl_xor(__float_as_int(acc[k]), 32, 64)));
        int p = slot + k * SLOTS;
        if (lane < 32) {
            smin[p][wave] = t;               // banks (17p+w)%32: 2-way, free
            if (wave == 0) sc2[p] = c2[k];
        }
    }
    __syncthreads();

    // ---- combine 16 wave-minima per point, mask, block-reduce ----
    float        v = 0.0f;
    unsigned int c = 0u;
    if (tid < PTSBLK) {
        float t = smin[tid][0];
        #pragma unroll
        for (int g = 1; g < WAVES; ++g) t = fminf(t, smin[tid][g]);
        float m = fmaxf(sc2[tid] + t, 0.0f);
        if (m < THRESH) { v = m; c = 1u; }
        #pragma unroll
        for (int off = 32; off >= 1; off >>= 1) {
            v += __shfl_down(v, off, 64);
            c += __shfl_down(c, off, 64);
        }
        if ((tid & 63) == 0) { rs[tid >> 6] = v; rc[tid >> 6] = c; }
    }
    __syncthreads();
    if (tid == 0) {
        float        bs = 0.0f;
        unsigned int bc = 0u;
        #pragma unroll
        for (int w = 0; w < PTSBLK / 64; ++w) { bs += rs[w]; bc += rc[w]; }
        // plain store to a private slot: no atomics, no fence, no ticket
        slots_out[blockIdx.x] = make_float2(bs, (float)bc);
    }
}

__global__ __launch_bounds__(256) void pml_fin(
    const float2* __restrict__ slots_in,
    float* __restrict__ out)
{
    const int tid = threadIdx.x;
    float2 sl = slots_in[tid];               // GRID == 256 == blockDim
    float s = sl.x, c = sl.y;
    #pragma unroll
    for (int off = 32; off >= 1; off >>= 1) {
        s += __shfl_down(s, off, 64);
        c += __shfl_down(c, off, 64);
    }
    __shared__ float ss[4], sc[4];
    if ((tid & 63) == 0) { ss[tid >> 6] = s; sc[tid >> 6] = c; }
    __syncthreads();
    if (tid == 0) {
        float s2 = ss[0] + ss[1] + ss[2] + ss[3];
        float c2 = sc[0] + sc[1] + sc[2] + sc[3];
        *out = (c2 > 0.0f) ? (s2 / (c2 + 1e-6f)) : 0.0f;   // WEIGHT = 1.0
    }
}

extern "C" void kernel_launch(void* const* d_in, const int* in_sizes, int n_in,
                              void* d_out, int out_size, void* d_ws, size_t ws_size,
                              hipStream_t stream) {
    const float* completed = (const float*)d_in[0];  // (8, 8192, 3) f32
    const float* partial   = (const float*)d_in[1];  // (8, 2048, 3) f32
    float* out = (float*)d_out;
    float2* slots = (float2*)d_ws;                   // 256 slots, all written
                                                     // before fin reads them:
                                                     // no memset node needed

    pml_main<<<dim3(GRID), dim3(1024), 0, stream>>>(completed, partial, slots);
    pml_fin<<<dim3(1), dim3(256), 0, stream>>>(slots, out);
}